// Round 3
// baseline (144.394 us; speedup 1.0000x reference)
//
#include <hip/hip_runtime.h>
#include <hip/hip_bf16.h>

typedef __attribute__((ext_vector_type(8))) short short8;
typedef __attribute__((ext_vector_type(8))) float f32x8;
typedef __attribute__((ext_vector_type(4))) float f32x4;
typedef unsigned short u16;

#define BQ 8
#define LL 2048
#define NN 1024
#define HH 64
#define BL (BQ * LL) /* 16384 */

static __device__ __forceinline__ u16 f2bf(float f) {
  union { float f; unsigned int u; } cv;
  cv.f = f;
  unsigned int u = cv.u;
  unsigned int rounded = u + 0x7FFFu + ((u >> 16) & 1u);  // RNE
  return (u16)(rounded >> 16);
}

// ---------------------------------------------------------------------------
// Kernel 0: wt[m][h][k] = bf16(W[m][k][h]) via LDS 64x64 tile transpose.
// grid = 3*16 blocks of 256 threads; coalesced f32 reads, 16B bf16 writes.
// ---------------------------------------------------------------------------
__global__ __launch_bounds__(256) void wt_pack(const float* __restrict__ Wq,
                                               const float* __restrict__ Wk,
                                               const float* __restrict__ Wv,
                                               u16* __restrict__ wt) {
  __shared__ u16 tile[64 * 65];
  const int bi = blockIdx.x;
  const int m = bi >> 4;
  const int k0 = (bi & 15) << 6;
  const float* src = (m == 0) ? Wq : (m == 1) ? Wk : Wv;
  const int t = threadIdx.x;
  {
    const int row = t >> 2;          // k within tile
    const int qd = t & 3;            // 16-col chunk
    const float4* sp = (const float4*)(src + (k0 + row) * HH + qd * 16);
#pragma unroll
    for (int j = 0; j < 4; ++j) {
      float4 v = sp[j];
      u16* d = &tile[row * 65 + qd * 16 + j * 4];
      d[0] = f2bf(v.x); d[1] = f2bf(v.y); d[2] = f2bf(v.z); d[3] = f2bf(v.w);
    }
  }
  __syncthreads();
  {
    const int h = t >> 2;
    const int kc = (t & 3) * 16;
    short8 o0, o1;
#pragma unroll
    for (int j = 0; j < 8; ++j) {
      o0[j] = (short)tile[(kc + j) * 65 + h];
      o1[j] = (short)tile[(kc + 8 + j) * 65 + h];
    }
    u16* dp = wt + m * (HH * NN) + h * NN + k0 + kc;
    *(short8*)dp = o0;
    *(short8*)(dp + 8) = o1;
  }
}

// ---------------------------------------------------------------------------
// Kernel 1: streaming qkv projection, 1 wave / 16 rows, no LDS, no barriers.
// q scaled by N^-0.5 = 1/32. v written TRANSPOSED: vsT[b][h][kv].
// ---------------------------------------------------------------------------
__global__ __launch_bounds__(64) void qkv_proj(const float* __restrict__ x,
                                               const u16* __restrict__ wt,
                                               u16* __restrict__ qs,
                                               u16* __restrict__ ks,
                                               u16* __restrict__ vsT) {
  const int bi = blockIdx.x;
  const int row0 = bi * 16;
  const int lane = threadIdx.x;
  const int r = lane & 15;
  const int g = lane >> 4;

  f32x4 acc[12] = {};
  const float* xp = x + (row0 + r) * NN + 8 * g;

#pragma unroll 2
  for (int k0 = 0; k0 < NN; k0 += 32) {
    f32x8 af = *(const f32x8*)(xp + k0);
    short8 a;
#pragma unroll
    for (int e = 0; e < 8; ++e) a[e] = (short)f2bf(af[e]);
#pragma unroll
    for (int m = 0; m < 3; ++m) {
#pragma unroll
      for (int nf = 0; nf < 4; ++nf) {
        short8 bf = *(const short8*)&wt[m * (HH * NN) + (nf * 16 + r) * NN + k0 + 8 * g];
        acc[m * 4 + nf] = __builtin_amdgcn_mfma_f32_16x16x32_bf16(a, bf, acc[m * 4 + nf], 0, 0, 0);
      }
    }
  }

  const int b = row0 >> 11;          // batch
  const int kvloc = row0 & (LL - 1); // kv base within batch
#pragma unroll
  for (int nf = 0; nf < 4; ++nf) {
#pragma unroll
    for (int rr = 0; rr < 4; ++rr) {
      const int row = row0 + 4 * g + rr;
      qs[row * HH + nf * 16 + r] = f2bf(acc[nf][rr] * 0.03125f);
      ks[row * HH + nf * 16 + r] = f2bf(acc[4 + nf][rr]);
      vsT[(b * HH + nf * 16 + r) * LL + kvloc + 4 * g + rr] = f2bf(acc[8 + nf][rr]);
    }
  }
}

// ---------------------------------------------------------------------------
// Kernel 2: causal flash attention. Block = (16-row q-tile, batch), 4 waves;
// wave w handles kv-tiles t ≡ w (mod 4) with private online-softmax state.
// No barriers in the loop; one end-merge via LDS. K, V^T read from global
// (L2-resident, batch pinned per XCD). Longest q-tiles scheduled first.
// ---------------------------------------------------------------------------
__global__ __launch_bounds__(256, 4) void attn(const u16* __restrict__ qs,
                                               const u16* __restrict__ ks,
                                               const u16* __restrict__ vsT,
                                               float* __restrict__ out) {
  __shared__ u16 P[4][16 * 72];        // per-wave P round-trip
  __shared__ float oM[4][16][64];      // merge: per-wave O partial
  __shared__ float mlM[4][2][16];      // merge: per-wave m, l

  const int bi = blockIdx.x;
  const int b = bi & 7;                // batch -> XCD pinning
  const int qt = 127 - (bi >> 3);      // longest first
  const int q0 = qt * 16;

  const int tid = threadIdx.x;
  const int lane = tid & 63;
  const int wv = tid >> 6;
  const int r = lane & 15;
  const int g = lane >> 4;

  const u16* qrow = &qs[(b * LL + q0 + r) * HH + 8 * g];
  const short8 qf0 = *(const short8*)qrow;
  const short8 qf1 = *(const short8*)(qrow + 32);

  float mrun[4], lrun[4];
  f32x4 o[4] = {};
#pragma unroll
  for (int rr = 0; rr < 4; ++rr) { mrun[rr] = -1e30f; lrun[rr] = 0.0f; }

  const int nt = (q0 + 16 + 63) >> 6;  // causal kv-tiles of 64

  for (int t = wv; t < nt; t += 4) {
    const int kv0 = t << 6;
    // ---- S = Q @ K^T
    f32x4 s4[4];
#pragma unroll
    for (int nf = 0; nf < 4; ++nf) {
      const u16* kp = &ks[(b * LL + kv0 + nf * 16 + r) * HH + 8 * g];
      short8 b0 = *(const short8*)kp;
      short8 b1 = *(const short8*)(kp + 32);
      f32x4 z = {};
      z = __builtin_amdgcn_mfma_f32_16x16x32_bf16(qf0, b0, z, 0, 0, 0);
      z = __builtin_amdgcn_mfma_f32_16x16x32_bf16(qf1, b1, z, 0, 0, 0);
      s4[nf] = z;
    }
    if (kv0 + 63 > q0) {  // diagonal-spanning tile: causal mask
#pragma unroll
      for (int nf = 0; nf < 4; ++nf) {
#pragma unroll
        for (int rr = 0; rr < 4; ++rr) {
          if (kv0 + nf * 16 + r > q0 + 4 * g + rr) s4[nf][rr] = -1e30f;
        }
      }
    }
    // ---- online softmax (rows live across the 16 r-lanes of each g-group)
    float pm[4];
#pragma unroll
    for (int rr = 0; rr < 4; ++rr)
      pm[rr] = fmaxf(fmaxf(s4[0][rr], s4[1][rr]), fmaxf(s4[2][rr], s4[3][rr]));
#pragma unroll
    for (int xm = 1; xm <= 8; xm <<= 1) {
#pragma unroll
      for (int rr = 0; rr < 4; ++rr)
        pm[rr] = fmaxf(pm[rr], __shfl_xor(pm[rr], xm));
    }
    float nm[4], al[4], rs[4];
#pragma unroll
    for (int rr = 0; rr < 4; ++rr) {
      nm[rr] = fmaxf(mrun[rr], pm[rr]);
      al[rr] = __expf(mrun[rr] - nm[rr]);
      rs[rr] = 0.0f;
    }
#pragma unroll
    for (int nf = 0; nf < 4; ++nf) {
#pragma unroll
      for (int rr = 0; rr < 4; ++rr) {
        float p = __expf(s4[nf][rr] - nm[rr]);
        s4[nf][rr] = p;
        rs[rr] += p;
      }
    }
#pragma unroll
    for (int xm = 1; xm <= 8; xm <<= 1) {
#pragma unroll
      for (int rr = 0; rr < 4; ++rr)
        rs[rr] += __shfl_xor(rs[rr], xm);
    }
#pragma unroll
    for (int rr = 0; rr < 4; ++rr) {
      lrun[rr] = lrun[rr] * al[rr] + rs[rr];
      mrun[rr] = nm[rr];
    }
#pragma unroll
    for (int hf = 0; hf < 4; ++hf) {
#pragma unroll
      for (int rr = 0; rr < 4; ++rr)
        o[hf][rr] *= al[rr];
    }
    // ---- P: D-layout -> per-wave LDS -> A-frag (same wave, no barrier)
#pragma unroll
    for (int nf = 0; nf < 4; ++nf) {
#pragma unroll
      for (int rr = 0; rr < 4; ++rr)
        P[wv][(4 * g + rr) * 72 + nf * 16 + r] = f2bf(s4[nf][rr]);
    }
    short8 pa0 = *(const short8*)&P[wv][r * 72 + 8 * g];
    short8 pa1 = *(const short8*)&P[wv][r * 72 + 32 + 8 * g];
    // ---- O += P @ V  (V^T fragments straight from global/L2)
#pragma unroll
    for (int hf = 0; hf < 4; ++hf) {
      const u16* vp = &vsT[(b * HH + hf * 16 + r) * LL + kv0 + 8 * g];
      short8 v0 = *(const short8*)vp;
      short8 v1 = *(const short8*)(vp + 32);
      o[hf] = __builtin_amdgcn_mfma_f32_16x16x32_bf16(pa0, v0, o[hf], 0, 0, 0);
      o[hf] = __builtin_amdgcn_mfma_f32_16x16x32_bf16(pa1, v1, o[hf], 0, 0, 0);
    }
  }

  // ---- merge the 4 per-wave partials
#pragma unroll
  for (int hf = 0; hf < 4; ++hf)
#pragma unroll
    for (int rr = 0; rr < 4; ++rr)
      oM[wv][4 * g + rr][hf * 16 + r] = o[hf][rr];
  if (r == 0) {
#pragma unroll
    for (int rr = 0; rr < 4; ++rr) {
      mlM[wv][0][4 * g + rr] = mrun[rr];
      mlM[wv][1][4 * g + rr] = lrun[rr];
    }
  }
  __syncthreads();

  {
    const int row = tid >> 4;          // 0..15
    const int hq = (tid & 15) * 4;     // 0..60
    float M = mlM[0][0][row];
#pragma unroll
    for (int w = 1; w < 4; ++w) M = fmaxf(M, mlM[w][0][row]);
    float L = 0.0f;
    float O0 = 0.0f, O1 = 0.0f, O2 = 0.0f, O3 = 0.0f;
#pragma unroll
    for (int w = 0; w < 4; ++w) {
      float al = __expf(mlM[w][0][row] - M);
      L += mlM[w][1][row] * al;
      O0 += oM[w][row][hq + 0] * al;
      O1 += oM[w][row][hq + 1] * al;
      O2 += oM[w][row][hq + 2] * al;
      O3 += oM[w][row][hq + 3] * al;
    }
    const float inv = 1.0f / L;
    float4 res = { O0 * inv, O1 * inv, O2 * inv, O3 * inv };
    *(float4*)&out[(b * LL + q0 + row) * HH + hq] = res;
  }
}

extern "C" void kernel_launch(void* const* d_in, const int* in_sizes, int n_in,
                              void* d_out, int out_size, void* d_ws, size_t ws_size,
                              hipStream_t stream) {
  const float* x  = (const float*)d_in[0];
  const float* Wk = (const float*)d_in[1];
  const float* Wq = (const float*)d_in[2];
  const float* Wv = (const float*)d_in[3];

  u16* qs  = (u16*)d_ws;             // [16384][64] bf16
  u16* ks  = qs + BL * HH;           // [16384][64] bf16
  u16* vsT = ks + BL * HH;           // [8][64][2048] bf16 (V transposed)
  u16* wt  = vsT + BL * HH;          // [3][64][1024] bf16 (W transposed)

  wt_pack<<<48, 256, 0, stream>>>(Wq, Wk, Wv, wt);
  qkv_proj<<<BL / 16, 64, 0, stream>>>(x, wt, qs, ks, vsT);
  attn<<<dim3(128 * BQ), 256, 0, stream>>>(qs, ks, vsT, (float*)d_out);
}

// Round 4
// 84.068 us; speedup vs baseline: 1.7176x; 1.7176x over previous
//
#include <hip/hip_runtime.h>
#include <hip/hip_bf16.h>

typedef __attribute__((ext_vector_type(8))) short short8;
typedef __attribute__((ext_vector_type(8))) float f32x8;
typedef __attribute__((ext_vector_type(4))) float f32x4;
typedef unsigned short u16;
typedef unsigned int u32;

#define BQ 8
#define LL 2048
#define NN 1024
#define HH 64
#define BL (BQ * LL) /* 16384 */

static __device__ __forceinline__ u16 f2bf(float f) {
  union { float f; unsigned int u; } cv;
  cv.f = f;
  unsigned int u = cv.u;
  unsigned int rounded = u + 0x7FFFu + ((u >> 16) & 1u);  // RNE
  return (u16)(rounded >> 16);
}

// pack 8 f32 -> 8 bf16 by truncation (1 v_perm per 2 elements)
static __device__ __forceinline__ short8 pack_bf16(f32x8 v) {
  short8 o;
  u32* op = (u32*)&o;
#pragma unroll
  for (int w = 0; w < 4; ++w) {
    op[w] = __builtin_amdgcn_perm(__float_as_uint(v[2 * w + 1]),
                                  __float_as_uint(v[2 * w]), 0x07060302u);
  }
  return o;
}

// ---------------------------------------------------------------------------
// Kernel 0: pack W into MFMA B-fragment order.
// frag f = (m*4 + nf)*32 + ks holds, contiguously, lane l's 8 bf16:
//   wtp[f*512 + l*8 + j] = bf16( W_m[ ks*32 + 8*(l>>4) + j ][ nf*16 + (l&15) ] )
// so a B-frag load in qkv_proj is one fully-coalesced 1KB wave load.
// ---------------------------------------------------------------------------
__global__ __launch_bounds__(256) void wtp_pack(const float* __restrict__ Wq,
                                                const float* __restrict__ Wk,
                                                const float* __restrict__ Wv,
                                                u16* __restrict__ wtp) {
  int gid = blockIdx.x * 256 + threadIdx.x;   // [0, 384*64)
  int f = gid >> 6;
  int l = gid & 63;
  int m = f >> 7;
  int rem = f & 127;
  int nf = rem >> 5;
  int ks = rem & 31;
  int r = l & 15;
  int g = l >> 4;
  const float* src = (m == 0) ? Wq : (m == 1) ? Wk : Wv;
  short8 o;
#pragma unroll
  for (int j = 0; j < 8; ++j)
    o[j] = (short)f2bf(src[(ks * 32 + 8 * g + j) * HH + nf * 16 + r]);
  *(short8*)&wtp[f * 512 + l * 8] = o;
}

// ---------------------------------------------------------------------------
// Kernel 1: qkv projection. Block = 192 threads = 3 waves sharing 16 x-rows;
// wave w computes matrix w (0=q scaled by 1/32, 1=k, 2=v transposed).
// B-frags are coalesced 1KB loads from wtp; x loaded once per wave (L1-shared).
// Epilogue through per-wave LDS tiles -> coalesced short8 stores.
// ---------------------------------------------------------------------------
__global__ __launch_bounds__(192) void qkv_proj(const float* __restrict__ x,
                                                const u16* __restrict__ wtp,
                                                u16* __restrict__ qs,
                                                u16* __restrict__ ks_,
                                                u16* __restrict__ vsT) {
  __shared__ u16 TL[3][1536];
  const int row0 = blockIdx.x * 16;
  const int tid = threadIdx.x;
  const int wv = tid >> 6;          // = m
  const int lane = tid & 63;
  const int r = lane & 15;
  const int g = lane >> 4;

  const u16* wpm = wtp + (wv << 16) + (lane << 3);
  const float* xp = x + (row0 + r) * NN + 8 * g;

  f32x4 acc[4] = {};
  f32x8 xn = *(const f32x8*)xp;

  for (int ks = 0; ks < 32; ++ks) {
    f32x8 xc = xn;
    if (ks < 31) xn = *(const f32x8*)(xp + (ks + 1) * 32);
    short8 a = pack_bf16(xc);
#pragma unroll
    for (int nf = 0; nf < 4; ++nf) {
      short8 bf = *(const short8*)(wpm + ((nf * 32 + ks) << 9));
      acc[nf] = __builtin_amdgcn_mfma_f32_16x16x32_bf16(a, bf, acc[nf], 0, 0, 0);
    }
    if ((ks & 7) == 7) __syncthreads();   // keep waves aligned for L1 x-reuse
  }

  const int b = row0 >> 11;
  const int kvloc = row0 & (LL - 1);
  u16* tl = TL[wv];

  if (wv < 2) {
    const float sc = (wv == 0) ? 0.03125f : 1.0f;
    u16* dst = (wv == 0) ? qs : ks_;
#pragma unroll
    for (int nf = 0; nf < 4; ++nf)
#pragma unroll
      for (int rr = 0; rr < 4; ++rr)
        tl[(4 * g + rr) * 72 + nf * 16 + r] = f2bf(acc[nf][rr] * sc);
    const int row = lane >> 2;
    const int c = (lane & 3) * 16;
    *(short8*)&dst[(row0 + row) * HH + c]     = *(short8*)&tl[row * 72 + c];
    *(short8*)&dst[(row0 + row) * HH + c + 8] = *(short8*)&tl[row * 72 + c + 8];
  } else {
    // v transposed: TL[h][kv], stride 24 (48B, 16B-aligned)
#pragma unroll
    for (int nf = 0; nf < 4; ++nf)
#pragma unroll
      for (int rr = 0; rr < 4; ++rr)
        tl[(nf * 16 + r) * 24 + 4 * g + rr] = f2bf(acc[nf][rr]);
    u16* dst = &vsT[((b * HH) + lane) * LL + kvloc];
    *(short8*)dst       = *(short8*)&tl[lane * 24];
    *(short8*)(dst + 8) = *(short8*)&tl[lane * 24 + 8];
  }
}

// ---------------------------------------------------------------------------
// Kernel 2: causal flash attention (unchanged from round 3).
// Block = (16-row q-tile, batch), 4 waves; wave w handles kv-tiles t ≡ w mod 4
// with private online-softmax state; one end-merge via LDS.
// ---------------------------------------------------------------------------
__global__ __launch_bounds__(256, 4) void attn(const u16* __restrict__ qs,
                                               const u16* __restrict__ ks,
                                               const u16* __restrict__ vsT,
                                               float* __restrict__ out) {
  __shared__ u16 P[4][16 * 72];
  __shared__ float oM[4][16][64];
  __shared__ float mlM[4][2][16];

  const int bi = blockIdx.x;
  const int b = bi & 7;
  const int qt = 127 - (bi >> 3);
  const int q0 = qt * 16;

  const int tid = threadIdx.x;
  const int lane = tid & 63;
  const int wv = tid >> 6;
  const int r = lane & 15;
  const int g = lane >> 4;

  const u16* qrow = &qs[(b * LL + q0 + r) * HH + 8 * g];
  const short8 qf0 = *(const short8*)qrow;
  const short8 qf1 = *(const short8*)(qrow + 32);

  float mrun[4], lrun[4];
  f32x4 o[4] = {};
#pragma unroll
  for (int rr = 0; rr < 4; ++rr) { mrun[rr] = -1e30f; lrun[rr] = 0.0f; }

  const int nt = (q0 + 16 + 63) >> 6;

  for (int t = wv; t < nt; t += 4) {
    const int kv0 = t << 6;
    f32x4 s4[4];
#pragma unroll
    for (int nf = 0; nf < 4; ++nf) {
      const u16* kp = &ks[(b * LL + kv0 + nf * 16 + r) * HH + 8 * g];
      short8 b0 = *(const short8*)kp;
      short8 b1 = *(const short8*)(kp + 32);
      f32x4 z = {};
      z = __builtin_amdgcn_mfma_f32_16x16x32_bf16(qf0, b0, z, 0, 0, 0);
      z = __builtin_amdgcn_mfma_f32_16x16x32_bf16(qf1, b1, z, 0, 0, 0);
      s4[nf] = z;
    }
    if (kv0 + 63 > q0) {
#pragma unroll
      for (int nf = 0; nf < 4; ++nf)
#pragma unroll
        for (int rr = 0; rr < 4; ++rr)
          if (kv0 + nf * 16 + r > q0 + 4 * g + rr) s4[nf][rr] = -1e30f;
    }
    float pm[4];
#pragma unroll
    for (int rr = 0; rr < 4; ++rr)
      pm[rr] = fmaxf(fmaxf(s4[0][rr], s4[1][rr]), fmaxf(s4[2][rr], s4[3][rr]));
#pragma unroll
    for (int xm = 1; xm <= 8; xm <<= 1)
#pragma unroll
      for (int rr = 0; rr < 4; ++rr)
        pm[rr] = fmaxf(pm[rr], __shfl_xor(pm[rr], xm));
    float nm[4], al[4], rs[4];
#pragma unroll
    for (int rr = 0; rr < 4; ++rr) {
      nm[rr] = fmaxf(mrun[rr], pm[rr]);
      al[rr] = __expf(mrun[rr] - nm[rr]);
      rs[rr] = 0.0f;
    }
#pragma unroll
    for (int nf = 0; nf < 4; ++nf)
#pragma unroll
      for (int rr = 0; rr < 4; ++rr) {
        float p = __expf(s4[nf][rr] - nm[rr]);
        s4[nf][rr] = p;
        rs[rr] += p;
      }
#pragma unroll
    for (int xm = 1; xm <= 8; xm <<= 1)
#pragma unroll
      for (int rr = 0; rr < 4; ++rr)
        rs[rr] += __shfl_xor(rs[rr], xm);
#pragma unroll
    for (int rr = 0; rr < 4; ++rr) {
      lrun[rr] = lrun[rr] * al[rr] + rs[rr];
      mrun[rr] = nm[rr];
    }
#pragma unroll
    for (int hf = 0; hf < 4; ++hf)
#pragma unroll
      for (int rr = 0; rr < 4; ++rr)
        o[hf][rr] *= al[rr];
#pragma unroll
    for (int nf = 0; nf < 4; ++nf)
#pragma unroll
      for (int rr = 0; rr < 4; ++rr)
        P[wv][(4 * g + rr) * 72 + nf * 16 + r] = f2bf(s4[nf][rr]);
    short8 pa0 = *(const short8*)&P[wv][r * 72 + 8 * g];
    short8 pa1 = *(const short8*)&P[wv][r * 72 + 32 + 8 * g];
#pragma unroll
    for (int hf = 0; hf < 4; ++hf) {
      const u16* vp = &vsT[(b * HH + hf * 16 + r) * LL + kv0 + 8 * g];
      short8 v0 = *(const short8*)vp;
      short8 v1 = *(const short8*)(vp + 32);
      o[hf] = __builtin_amdgcn_mfma_f32_16x16x32_bf16(pa0, v0, o[hf], 0, 0, 0);
      o[hf] = __builtin_amdgcn_mfma_f32_16x16x32_bf16(pa1, v1, o[hf], 0, 0, 0);
    }
  }

#pragma unroll
  for (int hf = 0; hf < 4; ++hf)
#pragma unroll
    for (int rr = 0; rr < 4; ++rr)
      oM[wv][4 * g + rr][hf * 16 + r] = o[hf][rr];
  if (r == 0) {
#pragma unroll
    for (int rr = 0; rr < 4; ++rr) {
      mlM[wv][0][4 * g + rr] = mrun[rr];
      mlM[wv][1][4 * g + rr] = lrun[rr];
    }
  }
  __syncthreads();

  {
    const int row = tid >> 4;
    const int hq = (tid & 15) * 4;
    float M = mlM[0][0][row];
#pragma unroll
    for (int w = 1; w < 4; ++w) M = fmaxf(M, mlM[w][0][row]);
    float L = 0.0f;
    float O0 = 0.0f, O1 = 0.0f, O2 = 0.0f, O3 = 0.0f;
#pragma unroll
    for (int w = 0; w < 4; ++w) {
      float al = __expf(mlM[w][0][row] - M);
      L += mlM[w][1][row] * al;
      O0 += oM[w][row][hq + 0] * al;
      O1 += oM[w][row][hq + 1] * al;
      O2 += oM[w][row][hq + 2] * al;
      O3 += oM[w][row][hq + 3] * al;
    }
    const float inv = 1.0f / L;
    float4 res = { O0 * inv, O1 * inv, O2 * inv, O3 * inv };
    *(float4*)&out[(b * LL + q0 + row) * HH + hq] = res;
  }
}

extern "C" void kernel_launch(void* const* d_in, const int* in_sizes, int n_in,
                              void* d_out, int out_size, void* d_ws, size_t ws_size,
                              hipStream_t stream) {
  const float* x  = (const float*)d_in[0];
  const float* Wk = (const float*)d_in[1];
  const float* Wq = (const float*)d_in[2];
  const float* Wv = (const float*)d_in[3];

  u16* qs  = (u16*)d_ws;             // [16384][64] bf16
  u16* ks  = qs + BL * HH;           // [16384][64] bf16
  u16* vsT = ks + BL * HH;           // [8][64][2048] bf16 (V transposed)
  u16* wtp = vsT + BL * HH;          // [384][512] bf16 (W in frag order)

  wtp_pack<<<96, 256, 0, stream>>>(Wq, Wk, Wv, wtp);
  qkv_proj<<<BL / 16, 192, 0, stream>>>(x, wtp, qs, ks, vsT);
  attn<<<dim3(128 * BQ), 256, 0, stream>>>(qs, ks, vsT, (float*)d_out);
}

// Round 5
// 83.945 us; speedup vs baseline: 1.7201x; 1.0015x over previous
//
#include <hip/hip_runtime.h>
#include <hip/hip_bf16.h>

typedef __attribute__((ext_vector_type(8))) short short8;
typedef __attribute__((ext_vector_type(8))) float f32x8;
typedef __attribute__((ext_vector_type(4))) float f32x4;
typedef unsigned short u16;
typedef unsigned int u32;

#define BQ 8
#define LL 2048
#define NN 1024
#define HH 64
#define BL (BQ * LL) /* 16384 */

static __device__ __forceinline__ u16 f2bf(float f) {
  union { float f; unsigned int u; } cv;
  cv.f = f;
  unsigned int u = cv.u;
  unsigned int rounded = u + 0x7FFFu + ((u >> 16) & 1u);  // RNE
  return (u16)(rounded >> 16);
}

// pack 8 f32 -> 8 bf16 by truncation (1 v_perm per 2 elements)
static __device__ __forceinline__ short8 pack_bf16(f32x8 v) {
  short8 o;
  u32* op = (u32*)&o;
#pragma unroll
  for (int w = 0; w < 4; ++w) {
    op[w] = __builtin_amdgcn_perm(__float_as_uint(v[2 * w + 1]),
                                  __float_as_uint(v[2 * w]), 0x07060302u);
  }
  return o;
}

// ---------------------------------------------------------------------------
// Kernel 0: pack W into MFMA B-fragment order.
// frag f = (m*4 + nf)*32 + ks holds, contiguously, lane l's 8 bf16:
//   wtp[f*512 + l*8 + j] = bf16( W_m[ ks*32 + 8*(l>>4) + j ][ nf*16 + (l&15) ] )
// ---------------------------------------------------------------------------
__global__ __launch_bounds__(256) void wtp_pack(const float* __restrict__ Wq,
                                                const float* __restrict__ Wk,
                                                const float* __restrict__ Wv,
                                                u16* __restrict__ wtp) {
  int gid = blockIdx.x * 256 + threadIdx.x;   // [0, 384*64)
  int f = gid >> 6;
  int l = gid & 63;
  int m = f >> 7;
  int rem = f & 127;
  int nf = rem >> 5;
  int ks = rem & 31;
  int r = l & 15;
  int g = l >> 4;
  const float* src = (m == 0) ? Wq : (m == 1) ? Wk : Wv;
  short8 o;
#pragma unroll
  for (int j = 0; j < 8; ++j)
    o[j] = (short)f2bf(src[(ks * 32 + 8 * g + j) * HH + nf * 16 + r]);
  *(short8*)&wtp[f * 512 + l * 8] = o;
}

// ---------------------------------------------------------------------------
// Kernel 1: qkv projection. Block = 384 threads = 6 waves over 16 x-rows;
// wave (m, kh) = (wv>>1, wv&1) computes matrix m over K-half kh.
// 6144 waves total = 6/SIMD. Per k-step: 1 x-load + 4 coalesced 1KB W-frag
// loads (prefetched) + 4 MFMA. kh-pairs merge f32 partials via LDS once.
// ---------------------------------------------------------------------------
__global__ __launch_bounds__(384) void qkv_proj(const float* __restrict__ x,
                                                const u16* __restrict__ wtp,
                                                u16* __restrict__ qs,
                                                u16* __restrict__ ks_,
                                                u16* __restrict__ vsT) {
  __shared__ float MG[3][16][64];   // kh=1 partials
  __shared__ u16 TL[3][1536];       // epilogue staging
  const int row0 = blockIdx.x * 16;
  const int tid = threadIdx.x;
  const int wv = tid / 64;
  const int m = wv >> 1;
  const int kh = wv & 1;
  const int lane = tid & 63;
  const int r = lane & 15;
  const int g = lane >> 4;

  const float* xp = x + (row0 + r) * NN + kh * 512 + 8 * g;
  // frag (nf, ks): wtp[ ((m*4+nf)*32 + kh*16 + ks) * 512 + lane*8 ]
  const u16* wp = wtp + ((m * 4 * 32 + kh * 16) << 9) + lane * 8;

  f32x4 acc[4] = {};
  f32x8 xn = *(const f32x8*)xp;
  short8 bfn[4];
#pragma unroll
  for (int nf = 0; nf < 4; ++nf)
    bfn[nf] = *(const short8*)(wp + ((nf * 32) << 9));

  for (int ks = 0; ks < 16; ++ks) {
    f32x8 xc = xn;
    short8 bfc[4];
#pragma unroll
    for (int nf = 0; nf < 4; ++nf) bfc[nf] = bfn[nf];
    if (ks < 15) {
      xn = *(const f32x8*)(xp + (ks + 1) * 32);
#pragma unroll
      for (int nf = 0; nf < 4; ++nf)
        bfn[nf] = *(const short8*)(wp + ((nf * 32 + ks + 1) << 9));
    }
    short8 a = pack_bf16(xc);
#pragma unroll
    for (int nf = 0; nf < 4; ++nf)
      acc[nf] = __builtin_amdgcn_mfma_f32_16x16x32_bf16(a, bfc[nf], acc[nf], 0, 0, 0);
  }

  // merge kh halves (f32) via LDS
  if (kh == 1) {
#pragma unroll
    for (int nf = 0; nf < 4; ++nf)
#pragma unroll
      for (int rr = 0; rr < 4; ++rr)
        MG[m][4 * g + rr][nf * 16 + r] = acc[nf][rr];
  }
  __syncthreads();
  if (kh == 0) {
#pragma unroll
    for (int nf = 0; nf < 4; ++nf)
#pragma unroll
      for (int rr = 0; rr < 4; ++rr)
        acc[nf][rr] += MG[m][4 * g + rr][nf * 16 + r];

    const int b = row0 >> 11;
    const int kvloc = row0 & (LL - 1);
    u16* tl = TL[m];
    if (m < 2) {
      const float sc = (m == 0) ? 0.03125f : 1.0f;
      u16* dst = (m == 0) ? qs : ks_;
#pragma unroll
      for (int nf = 0; nf < 4; ++nf)
#pragma unroll
        for (int rr = 0; rr < 4; ++rr)
          tl[(4 * g + rr) * 72 + nf * 16 + r] = f2bf(acc[nf][rr] * sc);
      const int row = lane >> 2;
      const int c = (lane & 3) * 16;
      *(short8*)&dst[(row0 + row) * HH + c]     = *(short8*)&tl[row * 72 + c];
      *(short8*)&dst[(row0 + row) * HH + c + 8] = *(short8*)&tl[row * 72 + c + 8];
    } else {
      // v transposed: TL[h][kv], stride 24
#pragma unroll
      for (int nf = 0; nf < 4; ++nf)
#pragma unroll
        for (int rr = 0; rr < 4; ++rr)
          tl[(nf * 16 + r) * 24 + 4 * g + rr] = f2bf(acc[nf][rr]);
      u16* dst = &vsT[((b * HH) + lane) * LL + kvloc];
      *(short8*)dst       = *(short8*)&tl[lane * 24];
      *(short8*)(dst + 8) = *(short8*)&tl[lane * 24 + 8];
    }
  }
}

// ---------------------------------------------------------------------------
// Kernel 2: causal flash attention (unchanged).
// ---------------------------------------------------------------------------
__global__ __launch_bounds__(256, 4) void attn(const u16* __restrict__ qs,
                                               const u16* __restrict__ ks,
                                               const u16* __restrict__ vsT,
                                               float* __restrict__ out) {
  __shared__ u16 P[4][16 * 72];
  __shared__ float oM[4][16][64];
  __shared__ float mlM[4][2][16];

  const int bi = blockIdx.x;
  const int b = bi & 7;
  const int qt = 127 - (bi >> 3);
  const int q0 = qt * 16;

  const int tid = threadIdx.x;
  const int lane = tid & 63;
  const int wv = tid >> 6;
  const int r = lane & 15;
  const int g = lane >> 4;

  const u16* qrow = &qs[(b * LL + q0 + r) * HH + 8 * g];
  const short8 qf0 = *(const short8*)qrow;
  const short8 qf1 = *(const short8*)(qrow + 32);

  float mrun[4], lrun[4];
  f32x4 o[4] = {};
#pragma unroll
  for (int rr = 0; rr < 4; ++rr) { mrun[rr] = -1e30f; lrun[rr] = 0.0f; }

  const int nt = (q0 + 16 + 63) >> 6;

  for (int t = wv; t < nt; t += 4) {
    const int kv0 = t << 6;
    f32x4 s4[4];
#pragma unroll
    for (int nf = 0; nf < 4; ++nf) {
      const u16* kp = &ks[(b * LL + kv0 + nf * 16 + r) * HH + 8 * g];
      short8 b0 = *(const short8*)kp;
      short8 b1 = *(const short8*)(kp + 32);
      f32x4 z = {};
      z = __builtin_amdgcn_mfma_f32_16x16x32_bf16(qf0, b0, z, 0, 0, 0);
      z = __builtin_amdgcn_mfma_f32_16x16x32_bf16(qf1, b1, z, 0, 0, 0);
      s4[nf] = z;
    }
    if (kv0 + 63 > q0) {
#pragma unroll
      for (int nf = 0; nf < 4; ++nf)
#pragma unroll
        for (int rr = 0; rr < 4; ++rr)
          if (kv0 + nf * 16 + r > q0 + 4 * g + rr) s4[nf][rr] = -1e30f;
    }
    float pm[4];
#pragma unroll
    for (int rr = 0; rr < 4; ++rr)
      pm[rr] = fmaxf(fmaxf(s4[0][rr], s4[1][rr]), fmaxf(s4[2][rr], s4[3][rr]));
#pragma unroll
    for (int xm = 1; xm <= 8; xm <<= 1)
#pragma unroll
      for (int rr = 0; rr < 4; ++rr)
        pm[rr] = fmaxf(pm[rr], __shfl_xor(pm[rr], xm));
    float nm[4], al[4], rs[4];
#pragma unroll
    for (int rr = 0; rr < 4; ++rr) {
      nm[rr] = fmaxf(mrun[rr], pm[rr]);
      al[rr] = __expf(mrun[rr] - nm[rr]);
      rs[rr] = 0.0f;
    }
#pragma unroll
    for (int nf = 0; nf < 4; ++nf)
#pragma unroll
      for (int rr = 0; rr < 4; ++rr) {
        float p = __expf(s4[nf][rr] - nm[rr]);
        s4[nf][rr] = p;
        rs[rr] += p;
      }
#pragma unroll
    for (int xm = 1; xm <= 8; xm <<= 1)
#pragma unroll
      for (int rr = 0; rr < 4; ++rr)
        rs[rr] += __shfl_xor(rs[rr], xm);
#pragma unroll
    for (int rr = 0; rr < 4; ++rr) {
      lrun[rr] = lrun[rr] * al[rr] + rs[rr];
      mrun[rr] = nm[rr];
    }
#pragma unroll
    for (int hf = 0; hf < 4; ++hf)
#pragma unroll
      for (int rr = 0; rr < 4; ++rr)
        o[hf][rr] *= al[rr];
#pragma unroll
    for (int nf = 0; nf < 4; ++nf)
#pragma unroll
      for (int rr = 0; rr < 4; ++rr)
        P[wv][(4 * g + rr) * 72 + nf * 16 + r] = f2bf(s4[nf][rr]);
    short8 pa0 = *(const short8*)&P[wv][r * 72 + 8 * g];
    short8 pa1 = *(const short8*)&P[wv][r * 72 + 32 + 8 * g];
#pragma unroll
    for (int hf = 0; hf < 4; ++hf) {
      const u16* vp = &vsT[(b * HH + hf * 16 + r) * LL + kv0 + 8 * g];
      short8 v0 = *(const short8*)vp;
      short8 v1 = *(const short8*)(vp + 32);
      o[hf] = __builtin_amdgcn_mfma_f32_16x16x32_bf16(pa0, v0, o[hf], 0, 0, 0);
      o[hf] = __builtin_amdgcn_mfma_f32_16x16x32_bf16(pa1, v1, o[hf], 0, 0, 0);
    }
  }

#pragma unroll
  for (int hf = 0; hf < 4; ++hf)
#pragma unroll
    for (int rr = 0; rr < 4; ++rr)
      oM[wv][4 * g + rr][hf * 16 + r] = o[hf][rr];
  if (r == 0) {
#pragma unroll
    for (int rr = 0; rr < 4; ++rr) {
      mlM[wv][0][4 * g + rr] = mrun[rr];
      mlM[wv][1][4 * g + rr] = lrun[rr];
    }
  }
  __syncthreads();

  {
    const int row = tid >> 4;
    const int hq = (tid & 15) * 4;
    float M = mlM[0][0][row];
#pragma unroll
    for (int w = 1; w < 4; ++w) M = fmaxf(M, mlM[w][0][row]);
    float L = 0.0f;
    float O0 = 0.0f, O1 = 0.0f, O2 = 0.0f, O3 = 0.0f;
#pragma unroll
    for (int w = 0; w < 4; ++w) {
      float al = __expf(mlM[w][0][row] - M);
      L += mlM[w][1][row] * al;
      O0 += oM[w][row][hq + 0] * al;
      O1 += oM[w][row][hq + 1] * al;
      O2 += oM[w][row][hq + 2] * al;
      O3 += oM[w][row][hq + 3] * al;
    }
    const float inv = 1.0f / L;
    float4 res = { O0 * inv, O1 * inv, O2 * inv, O3 * inv };
    *(float4*)&out[(b * LL + q0 + row) * HH + hq] = res;
  }
}

extern "C" void kernel_launch(void* const* d_in, const int* in_sizes, int n_in,
                              void* d_out, int out_size, void* d_ws, size_t ws_size,
                              hipStream_t stream) {
  const float* x  = (const float*)d_in[0];
  const float* Wk = (const float*)d_in[1];
  const float* Wq = (const float*)d_in[2];
  const float* Wv = (const float*)d_in[3];

  u16* qs  = (u16*)d_ws;             // [16384][64] bf16
  u16* ks  = qs + BL * HH;           // [16384][64] bf16
  u16* vsT = ks + BL * HH;           // [8][64][2048] bf16 (V transposed)
  u16* wtp = vsT + BL * HH;          // [384][512] bf16 (W in frag order)

  wtp_pack<<<96, 256, 0, stream>>>(Wq, Wk, Wv, wtp);
  qkv_proj<<<BL / 16, 384, 0, stream>>>(x, wtp, qs, ks, vsT);
  attn<<<dim3(128 * BQ), 256, 0, stream>>>(qs, ks, vsT, (float*)d_out);
}

// Round 6
// 68.967 us; speedup vs baseline: 2.0937x; 1.2172x over previous
//
#include <hip/hip_runtime.h>
#include <hip/hip_bf16.h>

typedef __attribute__((ext_vector_type(8))) short short8;
typedef __attribute__((ext_vector_type(8))) float f32x8;
typedef __attribute__((ext_vector_type(4))) float f32x4;
typedef unsigned short u16;
typedef unsigned int u32;

#define BQ 8
#define LL 2048
#define NN 1024
#define HH 64
#define BL (BQ * LL) /* 16384 */

static __device__ __forceinline__ u16 f2bf(float f) {
  union { float f; unsigned int u; } cv;
  cv.f = f;
  unsigned int u = cv.u;
  unsigned int rounded = u + 0x7FFFu + ((u >> 16) & 1u);  // RNE
  return (u16)(rounded >> 16);
}

// pack 8 f32 -> 8 bf16 by truncation (1 v_perm per 2 elements)
static __device__ __forceinline__ short8 pack_bf16(f32x8 v) {
  short8 o;
  u32* op = (u32*)&o;
#pragma unroll
  for (int w = 0; w < 4; ++w) {
    op[w] = __builtin_amdgcn_perm(__float_as_uint(v[2 * w + 1]),
                                  __float_as_uint(v[2 * w]), 0x07060302u);
  }
  return o;
}

// async global -> LDS, 16B per lane; lds dest must be wave-uniform base
static __device__ __forceinline__ void gload_lds16(const u16* g, u16* l) {
  __builtin_amdgcn_global_load_lds(
      (const __attribute__((address_space(1))) unsigned int*)g,
      (__attribute__((address_space(3))) unsigned int*)l, 16, 0, 0);
}

// ---------------------------------------------------------------------------
// Kernel 0: pack W into MFMA B-fragment order.
// frag f = (m*4 + nf)*32 + ks holds, contiguously, lane l's 8 bf16:
//   wtp[f*512 + l*8 + j] = bf16( W_m[ ks*32 + 8*(l>>4) + j ][ nf*16 + (l&15) ] )
// ---------------------------------------------------------------------------
__global__ __launch_bounds__(256) void wtp_pack(const float* __restrict__ Wq,
                                                const float* __restrict__ Wk,
                                                const float* __restrict__ Wv,
                                                u16* __restrict__ wtp) {
  int gid = blockIdx.x * 256 + threadIdx.x;   // [0, 384*64)
  int f = gid >> 6;
  int l = gid & 63;
  int m = f >> 7;
  int rem = f & 127;
  int nf = rem >> 5;
  int ks = rem & 31;
  int r = l & 15;
  int g = l >> 4;
  const float* src = (m == 0) ? Wq : (m == 1) ? Wk : Wv;
  short8 o;
#pragma unroll
  for (int j = 0; j < 8; ++j)
    o[j] = (short)f2bf(src[(ks * 32 + 8 * g + j) * HH + nf * 16 + r]);
  *(short8*)&wtp[f * 512 + l * 8] = o;
}

// ---------------------------------------------------------------------------
// Kernel 1: qkv projection, LDS-staged GEMM. Block = 64 rows x 192 cols,
// 512 threads = 8 waves = 2 row-halves (ms) x 4 F-quarters (fq, 3 frags each).
// K-chunks of 64, double-buffered: x f32->bf16 reg-staged (coalesced),
// W via global_load_lds into frag-linear LDS. One barrier per chunk.
// F = 0..11 maps (m = F>>2, nf = F&3): q = F0-3 (scaled 1/32), k = F4-7, v = F8-11.
// ---------------------------------------------------------------------------
__global__ __launch_bounds__(512, 4) void qkv_proj(const float* __restrict__ x,
                                                   const u16* __restrict__ wtp,
                                                   u16* __restrict__ qs,
                                                   u16* __restrict__ ks_,
                                                   u16* __restrict__ vsT) {
  __shared__ u16 xs[2][64 * 72];     // x tile, row stride 72 (144B, 16B-mult)
  __shared__ u16 ws[2][24 * 512];    // W frags: c = F*2 + ks, frag-linear

  const int row0 = blockIdx.x * 64;
  const int tid = threadIdx.x;
  const int wv = tid >> 6;
  const int lane = tid & 63;
  const int r = lane & 15;
  const int g = lane >> 4;
  const int ms = wv >> 2;            // 32-row half
  const int fq = wv & 3;             // 3-F quarter

  // x staging: thread reads 8 consecutive f32 (32B), 8 threads per row
  const int srow = tid >> 3;         // 0..63
  const int scol = (tid & 7) * 8;    // 0..56
  const float* xsrc = x + (row0 + srow) * NN + scol;

  f32x4 acc[2][3] = {};

  // ---- prologue: stage chunk 0 into buf 0
  {
    f32x8 xv = *(const f32x8*)xsrc;
    *(short8*)&xs[0][srow * 72 + scol] = pack_bf16(xv);
#pragma unroll
    for (int j = 0; j < 3; ++j) {
      int c = wv * 3 + j;
      int F = c >> 1, ks = c & 1;
      int gf = F * 32 + ks;          // kc = 0
      gload_lds16(wtp + gf * 512 + lane * 8, &ws[0][c * 512]);
    }
  }
  __syncthreads();

  int cur = 0;
  for (int kc = 0; kc < 16; ++kc) {
    // ---- prefetch chunk kc+1 into buf^1 (issue early, write x late)
    f32x8 xnv;
    if (kc < 15) {
      xnv = *(const f32x8*)(xsrc + (kc + 1) * 64);
#pragma unroll
      for (int j = 0; j < 3; ++j) {
        int c = wv * 3 + j;
        int F = c >> 1, ks = c & 1;
        int gf = F * 32 + (kc + 1) * 2 + ks;
        gload_lds16(wtp + gf * 512 + lane * 8, &ws[cur ^ 1][c * 512]);
      }
    }
    // ---- compute chunk kc from buf cur
#pragma unroll
    for (int ks = 0; ks < 2; ++ks) {
      short8 a[2];
#pragma unroll
      for (int mf = 0; mf < 2; ++mf)
        a[mf] = *(const short8*)&xs[cur][(ms * 32 + mf * 16 + r) * 72 + ks * 32 + 8 * g];
#pragma unroll
      for (int i = 0; i < 3; ++i) {
        int c = (fq * 3 + i) * 2 + ks;
        short8 bfr = *(const short8*)&ws[cur][c * 512 + lane * 8];
#pragma unroll
        for (int mf = 0; mf < 2; ++mf)
          acc[mf][i] = __builtin_amdgcn_mfma_f32_16x16x32_bf16(a[mf], bfr, acc[mf][i], 0, 0, 0);
      }
    }
    if (kc < 15)
      *(short8*)&xs[cur ^ 1][srow * 72 + scol] = pack_bf16(xnv);
    __syncthreads();
    cur ^= 1;
  }

  // ---- epilogue
  const int b = row0 >> 11;
  const int kvloc = row0 & (LL - 1);
  u16* vt = xs[0];                   // reuse: vt[h][kvcol], stride 72
#pragma unroll
  for (int mf = 0; mf < 2; ++mf) {
#pragma unroll
    for (int i = 0; i < 3; ++i) {
      const int F = fq * 3 + i, m = F >> 2, nf = F & 3;
      const int rowb = row0 + ms * 32 + mf * 16;
      if (m == 0) {
#pragma unroll
        for (int rr = 0; rr < 4; ++rr)
          qs[(rowb + 4 * g + rr) * HH + nf * 16 + r] = f2bf(acc[mf][i][rr] * 0.03125f);
      } else if (m == 1) {
#pragma unroll
        for (int rr = 0; rr < 4; ++rr)
          ks_[(rowb + 4 * g + rr) * HH + nf * 16 + r] = f2bf(acc[mf][i][rr]);
      } else {
#pragma unroll
        for (int rr = 0; rr < 4; ++rr)
          vt[(nf * 16 + r) * 72 + ms * 32 + mf * 16 + 4 * g + rr] = f2bf(acc[mf][i][rr]);
      }
    }
  }
  __syncthreads();
  if (tid < 256) {
    const int h = tid >> 2;
    const int seg = (tid & 3) * 16;
    const u16* s = &vt[h * 72 + seg];
    u16* d = &vsT[(b * HH + h) * LL + kvloc + seg];
    *(short8*)d = *(short8*)s;
    *(short8*)(d + 8) = *(short8*)(s + 8);
  }
}

// ---------------------------------------------------------------------------
// Kernel 2: causal flash attention (unchanged).
// ---------------------------------------------------------------------------
__global__ __launch_bounds__(256, 4) void attn(const u16* __restrict__ qs,
                                               const u16* __restrict__ ks,
                                               const u16* __restrict__ vsT,
                                               float* __restrict__ out) {
  __shared__ u16 P[4][16 * 72];
  __shared__ float oM[4][16][64];
  __shared__ float mlM[4][2][16];

  const int bi = blockIdx.x;
  const int b = bi & 7;
  const int qt = 127 - (bi >> 3);
  const int q0 = qt * 16;

  const int tid = threadIdx.x;
  const int lane = tid & 63;
  const int wv = tid >> 6;
  const int r = lane & 15;
  const int g = lane >> 4;

  const u16* qrow = &qs[(b * LL + q0 + r) * HH + 8 * g];
  const short8 qf0 = *(const short8*)qrow;
  const short8 qf1 = *(const short8*)(qrow + 32);

  float mrun[4], lrun[4];
  f32x4 o[4] = {};
#pragma unroll
  for (int rr = 0; rr < 4; ++rr) { mrun[rr] = -1e30f; lrun[rr] = 0.0f; }

  const int nt = (q0 + 16 + 63) >> 6;

  for (int t = wv; t < nt; t += 4) {
    const int kv0 = t << 6;
    f32x4 s4[4];
#pragma unroll
    for (int nf = 0; nf < 4; ++nf) {
      const u16* kp = &ks[(b * LL + kv0 + nf * 16 + r) * HH + 8 * g];
      short8 b0 = *(const short8*)kp;
      short8 b1 = *(const short8*)(kp + 32);
      f32x4 z = {};
      z = __builtin_amdgcn_mfma_f32_16x16x32_bf16(qf0, b0, z, 0, 0, 0);
      z = __builtin_amdgcn_mfma_f32_16x16x32_bf16(qf1, b1, z, 0, 0, 0);
      s4[nf] = z;
    }
    if (kv0 + 63 > q0) {
#pragma unroll
      for (int nf = 0; nf < 4; ++nf)
#pragma unroll
        for (int rr = 0; rr < 4; ++rr)
          if (kv0 + nf * 16 + r > q0 + 4 * g + rr) s4[nf][rr] = -1e30f;
    }
    float pm[4];
#pragma unroll
    for (int rr = 0; rr < 4; ++rr)
      pm[rr] = fmaxf(fmaxf(s4[0][rr], s4[1][rr]), fmaxf(s4[2][rr], s4[3][rr]));
#pragma unroll
    for (int xm = 1; xm <= 8; xm <<= 1)
#pragma unroll
      for (int rr = 0; rr < 4; ++rr)
        pm[rr] = fmaxf(pm[rr], __shfl_xor(pm[rr], xm));
    float nm[4], al[4], rs[4];
#pragma unroll
    for (int rr = 0; rr < 4; ++rr) {
      nm[rr] = fmaxf(mrun[rr], pm[rr]);
      al[rr] = __expf(mrun[rr] - nm[rr]);
      rs[rr] = 0.0f;
    }
#pragma unroll
    for (int nf = 0; nf < 4; ++nf)
#pragma unroll
      for (int rr = 0; rr < 4; ++rr) {
        float p = __expf(s4[nf][rr] - nm[rr]);
        s4[nf][rr] = p;
        rs[rr] += p;
      }
#pragma unroll
    for (int xm = 1; xm <= 8; xm <<= 1)
#pragma unroll
      for (int rr = 0; rr < 4; ++rr)
        rs[rr] += __shfl_xor(rs[rr], xm);
#pragma unroll
    for (int rr = 0; rr < 4; ++rr) {
      lrun[rr] = lrun[rr] * al[rr] + rs[rr];
      mrun[rr] = nm[rr];
    }
#pragma unroll
    for (int hf = 0; hf < 4; ++hf)
#pragma unroll
      for (int rr = 0; rr < 4; ++rr)
        o[hf][rr] *= al[rr];
#pragma unroll
    for (int nf = 0; nf < 4; ++nf)
#pragma unroll
      for (int rr = 0; rr < 4; ++rr)
        P[wv][(4 * g + rr) * 72 + nf * 16 + r] = f2bf(s4[nf][rr]);
    short8 pa0 = *(const short8*)&P[wv][r * 72 + 8 * g];
    short8 pa1 = *(const short8*)&P[wv][r * 72 + 32 + 8 * g];
#pragma unroll
    for (int hf = 0; hf < 4; ++hf) {
      const u16* vp = &vsT[(b * HH + hf * 16 + r) * LL + kv0 + 8 * g];
      short8 v0 = *(const short8*)vp;
      short8 v1 = *(const short8*)(vp + 32);
      o[hf] = __builtin_amdgcn_mfma_f32_16x16x32_bf16(pa0, v0, o[hf], 0, 0, 0);
      o[hf] = __builtin_amdgcn_mfma_f32_16x16x32_bf16(pa1, v1, o[hf], 0, 0, 0);
    }
  }

#pragma unroll
  for (int hf = 0; hf < 4; ++hf)
#pragma unroll
    for (int rr = 0; rr < 4; ++rr)
      oM[wv][4 * g + rr][hf * 16 + r] = o[hf][rr];
  if (r == 0) {
#pragma unroll
    for (int rr = 0; rr < 4; ++rr) {
      mlM[wv][0][4 * g + rr] = mrun[rr];
      mlM[wv][1][4 * g + rr] = lrun[rr];
    }
  }
  __syncthreads();

  {
    const int row = tid >> 4;
    const int hq = (tid & 15) * 4;
    float M = mlM[0][0][row];
#pragma unroll
    for (int w = 1; w < 4; ++w) M = fmaxf(M, mlM[w][0][row]);
    float L = 0.0f;
    float O0 = 0.0f, O1 = 0.0f, O2 = 0.0f, O3 = 0.0f;
#pragma unroll
    for (int w = 0; w < 4; ++w) {
      float al = __expf(mlM[w][0][row] - M);
      L += mlM[w][1][row] * al;
      O0 += oM[w][row][hq + 0] * al;
      O1 += oM[w][row][hq + 1] * al;
      O2 += oM[w][row][hq + 2] * al;
      O3 += oM[w][row][hq + 3] * al;
    }
    const float inv = 1.0f / L;
    float4 res = { O0 * inv, O1 * inv, O2 * inv, O3 * inv };
    *(float4*)&out[(b * LL + q0 + row) * HH + hq] = res;
  }
}

extern "C" void kernel_launch(void* const* d_in, const int* in_sizes, int n_in,
                              void* d_out, int out_size, void* d_ws, size_t ws_size,
                              hipStream_t stream) {
  const float* x  = (const float*)d_in[0];
  const float* Wk = (const float*)d_in[1];
  const float* Wq = (const float*)d_in[2];
  const float* Wv = (const float*)d_in[3];

  u16* qs  = (u16*)d_ws;             // [16384][64] bf16
  u16* ks  = qs + BL * HH;           // [16384][64] bf16
  u16* vsT = ks + BL * HH;           // [8][64][2048] bf16 (V transposed)
  u16* wtp = vsT + BL * HH;          // [384][512] bf16 (W in frag order)

  wtp_pack<<<96, 256, 0, stream>>>(Wq, Wk, Wv, wtp);
  qkv_proj<<<BL / 64, 512, 0, stream>>>(x, wtp, qs, ks, vsT);
  attn<<<dim3(128 * BQ), 256, 0, stream>>>(qs, ks, vsT, (float*)d_out);
}